// Round 10
// baseline (454.426 us; speedup 1.0000x reference)
//
#include <hip/hip_runtime.h>
#include <cstddef>

#define D 256
#define H 8
#define HD 32
#define ED 64
#define TPB 4

typedef __attribute__((ext_vector_type(8))) short short8;
typedef __attribute__((ext_vector_type(4))) short short4v;
typedef __attribute__((ext_vector_type(4))) float floatx4;

// fp32 -> bf16 RNE
__device__ inline short f2bf(float f) {
    unsigned u = __float_as_uint(f);
    unsigned r = (u + 0x7fffu + ((u >> 16) & 1u)) >> 16;
    return (short)r;
}

// ---------------- activations ----------------
template<int ACT> __device__ inline float act_f(float v) {
    if (ACT == 1) return fmaxf(v, 0.f);
    if (ACT == 2) return v > 0.f ? v : expm1f(v);              // elu
    if (ACT == 3) return 0.5f * v * (1.f + erff(v * 0.70710678118654752f)); // exact gelu
    return v;
}

__device__ inline float wave_sum(float v) {
#pragma unroll
    for (int off = 32; off > 0; off >>= 1) v += __shfl_xor(v, off, 64);
    return v;
}

// ================= fused prep: all weight conversions + cnt zero + h init =========
__global__ void prep_kernel(
        const float* __restrict__ Wl, const float* __restrict__ W1,
        const float* __restrict__ W2, const float* __restrict__ in_w,
        const float* __restrict__ outw, const float* __restrict__ Wf1,
        const float* __restrict__ Wf2, const float* __restrict__ x,
        const float* __restrict__ eps,
        short* __restrict__ WlT, short* __restrict__ W1bt, short* __restrict__ W2bt,
        short* __restrict__ inwbt, short* __restrict__ outwbt,
        short* __restrict__ Wf1bt, short* __restrict__ Wf2bt,
        int* __restrict__ cnt, float* __restrict__ h, int N, int NF) {
    int idx = blockIdx.x * 256 + threadIdx.x;
    if (idx < 16384) { int n = idx >> 6, k = idx & 63; WlT[idx] = f2bf(Wl[k * 256 + n]); return; }
    idx -= 16384;
    if (idx < 65536) { int n = idx >> 8, k = idx & 255; W1bt[idx] = f2bf(W1[k * 256 + n]); return; }
    idx -= 65536;
    if (idx < 65536) { int n = idx >> 8, k = idx & 255; W2bt[idx] = f2bf(W2[k * 256 + n]); return; }
    idx -= 65536;
    if (idx < 196608) { inwbt[idx] = f2bf(in_w[idx]); return; }
    idx -= 196608;
    if (idx < 65536) { outwbt[idx] = f2bf(outw[idx]); return; }
    idx -= 65536;
    if (idx < 131072) { int n = idx >> 8, k = idx & 255; Wf1bt[idx] = f2bf(Wf1[k * 512 + n]); return; }
    idx -= 131072;
    if (idx < 131072) { int n = idx >> 9, k = idx & 511; Wf2bt[idx] = f2bf(Wf2[k * 256 + n]); return; }
    idx -= 131072;
    if (idx < N) { cnt[idx] = 0; return; }
    idx -= N;
    if (idx < NF) { h[idx] = (1.f + eps[0]) * x[idx]; }
}

// ================= edge binning =================
__global__ void hist_kernel(const int* __restrict__ ei, int* __restrict__ cnt, int E) {
    int e = blockIdx.x * 256 + threadIdx.x;
    if (e < E) atomicAdd(&cnt[ei[E + e]], 1);
}

__global__ __launch_bounds__(1024) void scan_kernel(int* __restrict__ cnt,
                                                    int* __restrict__ offs) {
    __shared__ int s[1024];
    int tid = threadIdx.x;
    int4 c = *(int4*)&cnt[tid * 4];
    int sum = c.x + c.y + c.z + c.w;
    s[tid] = sum;
    __syncthreads();
    for (int off = 1; off < 1024; off <<= 1) {
        int v = (tid >= off) ? s[tid - off] : 0;
        __syncthreads();
        s[tid] += v;
        __syncthreads();
    }
    int ex = s[tid] - sum;
    int o1 = ex + c.x, o2 = o1 + c.y, o3 = o2 + c.z;
    offs[tid * 4] = ex; offs[tid * 4 + 1] = o1;
    offs[tid * 4 + 2] = o2; offs[tid * 4 + 3] = o3;
    cnt[tid * 4] = ex; cnt[tid * 4 + 1] = o1;
    cnt[tid * 4 + 2] = o2; cnt[tid * 4 + 3] = o3;
    if (tid == 1023) offs[4096] = s[1023];
}

__global__ void scatter_kernel(const int* __restrict__ ei, int* __restrict__ cursor,
                               int* __restrict__ perm, int* __restrict__ srcp,
                               int* __restrict__ dstp, int E) {
    int e = blockIdx.x * 256 + threadIdx.x;
    if (e < E) {
        int d = ei[E + e];
        int pos = atomicAdd(&cursor[d], 1);
        perm[pos] = e;
        srcp[pos] = ei[e];
        dstp[pos] = d;
    }
}

// Fused GINE edge kernel: 4 tiles of 64 edges per block, double-buffered LDS.
__global__ __launch_bounds__(256) void edge_fused_kernel(
        const float* __restrict__ ea, const short* __restrict__ WlT,
        const float* __restrict__ bl, const float* __restrict__ x,
        const int* __restrict__ perm, const int* __restrict__ srcp,
        const int* __restrict__ dstp, float* __restrict__ h) {
    __shared__ __align__(16) short ea_s[2][64 * 72];
    int tid = threadIdx.x;
    int wave = tid >> 6, lane = tid & 63;
    int mm = lane & 15, quad = lane >> 4;
    int base_e = blockIdx.x * (64 * TPB);

    int myperm[TPB], mysrc[TPB], mydst[TPB];
#pragma unroll
    for (int t = 0; t < TPB; t++) {
        myperm[t] = perm[base_e + t * 64 + lane];
        mysrc[t]  = srcp[base_e + t * 64 + lane];
        mydst[t]  = dstp[base_e + t * 64 + lane];
    }
    short8 af[4][2];
#pragma unroll
    for (int t = 0; t < 4; t++)
#pragma unroll
        for (int q2 = 0; q2 < 2; q2++)
            af[t][q2] = *(const short8*)&WlT[(wave * 64 + t * 16 + mm) * 64 + q2 * 32 + quad * 8];
    float4 blv[4];
#pragma unroll
    for (int t = 0; t < 4; t++)
        blv[t] = *(const float4*)&bl[wave * 64 + t * 16 + quad * 4];

    {
        float4 r[4];
#pragma unroll
        for (int p = 0; p < 4; p++) {
            int slot = tid + p * 256;
            int row = slot >> 4, c4 = slot & 15;
            int prow = __shfl(myperm[0], row);
            r[p] = *(const float4*)&ea[(size_t)prow * ED + c4 * 4];
        }
#pragma unroll
        for (int p = 0; p < 4; p++) {
            int slot = tid + p * 256;
            int row = slot >> 4, c4 = slot & 15;
            short4v s; s[0] = f2bf(r[p].x); s[1] = f2bf(r[p].y); s[2] = f2bf(r[p].z); s[3] = f2bf(r[p].w);
            *(short4v*)&ea_s[0][row * 72 + c4 * 4] = s;
        }
    }
    __syncthreads();

#pragma unroll
    for (int t = 0; t < TPB; t++) {
        const int buf = t & 1;
        float4 pre[4];
        if (t + 1 < TPB) {
#pragma unroll
            for (int p = 0; p < 4; p++) {
                int slot = tid + p * 256;
                int row = slot >> 4, c4 = slot & 15;
                int prow = __shfl(myperm[t + 1], row);
                pre[p] = *(const float4*)&ea[(size_t)prow * ED + c4 * 4];
            }
        }
        floatx4 acc[4][4];
#pragma unroll
        for (int et = 0; et < 4; et++)
#pragma unroll
            for (int tt = 0; tt < 4; tt++) acc[et][tt] = (floatx4){0.f, 0.f, 0.f, 0.f};
#pragma unroll
        for (int et = 0; et < 4; et++) {
            short8 bf0 = *(const short8*)&ea_s[buf][(et * 16 + mm) * 72 + quad * 8];
            short8 bf1 = *(const short8*)&ea_s[buf][(et * 16 + mm) * 72 + 32 + quad * 8];
#pragma unroll
            for (int tt = 0; tt < 4; tt++) {
                acc[et][tt] = __builtin_amdgcn_mfma_f32_16x16x32_bf16(af[tt][0], bf0, acc[et][tt], 0, 0, 0);
                acc[et][tt] = __builtin_amdgcn_mfma_f32_16x16x32_bf16(af[tt][1], bf1, acc[et][tt], 0, 0, 0);
            }
        }
#pragma unroll
        for (int et = 0; et < 4; et++) {
            int srci = __shfl(mysrc[t], et * 16 + mm);
            const float* xrow = x + (size_t)srci * D + wave * 64 + quad * 4;
#pragma unroll
            for (int tt = 0; tt < 4; tt++) {
                float4 xv = *(const float4*)(xrow + tt * 16);
                acc[et][tt][0] = fmaxf(acc[et][tt][0] + blv[tt].x + xv.x, 0.f);
                acc[et][tt][1] = fmaxf(acc[et][tt][1] + blv[tt].y + xv.y, 0.f);
                acc[et][tt][2] = fmaxf(acc[et][tt][2] + blv[tt].z + xv.z, 0.f);
                acc[et][tt][3] = fmaxf(acc[et][tt][3] + blv[tt].w + xv.w, 0.f);
            }
        }
        int prevd = __shfl_up(mydst[t], 1);
        bool bnd = (lane == 0) || (mydst[t] != prevd);
        unsigned long long m = __ballot(bnd);
        while (m) {
            int segstart = (int)__builtin_ctzll(m);
            m &= m - 1;
            int segend = m ? (int)__builtin_ctzll(m) : 64;
            int segdst = __shfl(mydst[t], segstart);
            bool in0 = (0 * 16 + mm >= segstart) & (0 * 16 + mm < segend);
            bool in1 = (1 * 16 + mm >= segstart) & (1 * 16 + mm < segend);
            bool in2 = (2 * 16 + mm >= segstart) & (2 * 16 + mm < segend);
            bool in3 = (3 * 16 + mm >= segstart) & (3 * 16 + mm < segend);
            float* hrow = h + (size_t)segdst * D + wave * 64;
#pragma unroll
            for (int tt = 0; tt < 4; tt++) {
#pragma unroll
                for (int j = 0; j < 4; j++) {
                    float v = (in0 ? acc[0][tt][j] : 0.f) + (in1 ? acc[1][tt][j] : 0.f)
                            + (in2 ? acc[2][tt][j] : 0.f) + (in3 ? acc[3][tt][j] : 0.f);
                    v += __shfl_xor(v, 1);
                    v += __shfl_xor(v, 2);
                    v += __shfl_xor(v, 4);
                    v += __shfl_xor(v, 8);
                    if (mm == 0) atomicAdd(&hrow[tt * 16 + quad * 4 + j], v);
                }
            }
        }
        if (t + 1 < TPB) {
#pragma unroll
            for (int p = 0; p < 4; p++) {
                int slot = tid + p * 256;
                int row = slot >> 4, c4 = slot & 15;
                short4v s; s[0] = f2bf(pre[p].x); s[1] = f2bf(pre[p].y);
                s[2] = f2bf(pre[p].z); s[3] = f2bf(pre[p].w);
                *(short4v*)&ea_s[1 - buf][row * 72 + c4 * 4] = s;
            }
            __syncthreads();
        }
    }
}

// ---------------- bf16 MFMA GEMM, BK=64: C = act(A @ Bt^T + bias) ----------------
#define GSTR 72
template<int ACT>
__global__ __launch_bounds__(256) void gemm_bf16_kernel(
        const float* __restrict__ A, const short* __restrict__ Bt,
        const float* __restrict__ bias, float* __restrict__ C,
        int M, int K, int Nc) {
    __shared__ __align__(16) short As[64 * GSTR];
    __shared__ __align__(16) short Bs[64 * GSTR];
    int tid = threadIdx.x;
    int wave = tid >> 6, lane = tid & 63;
    int mm = lane & 15, quad = lane >> 4;
    int wm = wave >> 1, wn = wave & 1;
    int m0 = blockIdx.y * 64, n0 = blockIdx.x * 64;
    floatx4 acc[2][2];
#pragma unroll
    for (int i = 0; i < 2; i++)
#pragma unroll
        for (int j = 0; j < 2; j++) acc[i][j] = (floatx4){0.f, 0.f, 0.f, 0.f};
    for (int k0 = 0; k0 < K; k0 += 64) {
        // A: 64 rows x 64 cols fp32 -> bf16 (1024 float4 slots, 4/thread)
#pragma unroll
        for (int p = 0; p < 4; p++) {
            int slot = tid + p * 256;
            int row = slot >> 4, c4 = slot & 15;
            float4 v = *(const float4*)&A[(size_t)(m0 + row) * K + k0 + c4 * 4];
            short4v s; s[0] = f2bf(v.x); s[1] = f2bf(v.y); s[2] = f2bf(v.z); s[3] = f2bf(v.w);
            *(short4v*)&As[row * GSTR + c4 * 4] = s;
        }
        // B: 64 rows x 64 cols bf16 (512 short8 slots, 2/thread)
#pragma unroll
        for (int p = 0; p < 2; p++) {
            int slot = tid + p * 256;
            int row = slot >> 3, seg = slot & 7;
            short8 v = *(const short8*)&Bt[(size_t)(n0 + row) * K + k0 + seg * 8];
            *(short8*)&Bs[row * GSTR + seg * 8] = v;
        }
        __syncthreads();
        short8 af[2][2], bf[2][2];
#pragma unroll
        for (int t = 0; t < 2; t++)
#pragma unroll
            for (int q2 = 0; q2 < 2; q2++) {
                af[t][q2] = *(const short8*)&As[(wm * 32 + t * 16 + mm) * GSTR + q2 * 32 + quad * 8];
                bf[t][q2] = *(const short8*)&Bs[(wn * 32 + t * 16 + mm) * GSTR + q2 * 32 + quad * 8];
            }
#pragma unroll
        for (int i = 0; i < 2; i++)
#pragma unroll
            for (int j = 0; j < 2; j++) {
                acc[i][j] = __builtin_amdgcn_mfma_f32_16x16x32_bf16(af[i][0], bf[j][0], acc[i][j], 0, 0, 0);
                acc[i][j] = __builtin_amdgcn_mfma_f32_16x16x32_bf16(af[i][1], bf[j][1], acc[i][j], 0, 0, 0);
            }
        __syncthreads();
    }
#pragma unroll
    for (int i = 0; i < 2; i++) {
#pragma unroll
        for (int j = 0; j < 2; j++) {
            int ncol = n0 + wn * 32 + j * 16 + mm;
            float bv = bias[ncol];
#pragma unroll
            for (int r = 0; r < 4; r++) {
                int mrow = m0 + wm * 32 + i * 16 + quad * 4 + r;
                C[(size_t)mrow * Nc + ncol] = act_f<ACT>(acc[i][j][r] + bv);
            }
        }
    }
}

// ---------------- row LayerNorm + optional ELU + residual ----------------
template<int ACT>
__global__ __launch_bounds__(256) void ln_res_kernel(
        const float* __restrict__ t, const float* __restrict__ res,
        const float* __restrict__ g, const float* __restrict__ b,
        float* __restrict__ out) {
    __shared__ float red[8];
    int row = blockIdx.x, tid = threadIdx.x;
    float v = t[(size_t)row * D + tid];
    int wid = tid >> 6, lane = tid & 63;
    float s = wave_sum(v);
    if (lane == 0) red[wid] = s;
    __syncthreads();
    float mu = (red[0] + red[1] + red[2] + red[3]) * (1.f / D);
    float dv = v - mu;
    float s2 = wave_sum(dv * dv);
    if (lane == 0) red[4 + wid] = s2;
    __syncthreads();
    float var = (red[4] + red[5] + red[6] + red[7]) * (1.f / D);
    float y = dv * rsqrtf(var + 1e-5f) * g[tid] + b[tid];
    y = act_f<ACT>(y);
    out[(size_t)row * D + tid] = res[(size_t)row * D + tid] + y;
}

// ---------------- MFMA flash attention, 4 q-frags/wave (256 q-rows/block) ----------
#define KSTR 40
#define VSTR 136
#define ATILE 128
#define AQF 4
__global__ __launch_bounds__(256) void attn_mfma_kernel(
        const float* __restrict__ qkv, float* __restrict__ po,
        float* __restrict__ pm, float* __restrict__ pl, int N, int KC_) {
    __shared__ __align__(16) short Ks[ATILE * KSTR];
    __shared__ __align__(16) short VTs[HD * VSTR];
    const int tid = threadIdx.x;
    const int wave = tid >> 6, lane = tid & 63;
    const int mm = lane & 15, quad = lane >> 4;
    const int h = blockIdx.y, c = blockIdx.z;
    const int qbase = blockIdx.x * 256 + wave * 64;   // wave covers 64 q rows, 4 frags
    const float scale = 0.17677669529663687f; // 1/sqrt(32)

    short8 qf[AQF];
#pragma unroll
    for (int f = 0; f < AQF; f++) {
        const float* qrow = qkv + (size_t)(qbase + f * 16 + mm) * (3 * D) + h * HD + quad * 8;
        float4 a = *(const float4*)qrow;
        float4 b = *(const float4*)(qrow + 4);
        qf[f][0] = f2bf(a.x * scale); qf[f][1] = f2bf(a.y * scale);
        qf[f][2] = f2bf(a.z * scale); qf[f][3] = f2bf(a.w * scale);
        qf[f][4] = f2bf(b.x * scale); qf[f][5] = f2bf(b.y * scale);
        qf[f][6] = f2bf(b.z * scale); qf[f][7] = f2bf(b.w * scale);
    }
    floatx4 accA[AQF], accB[AQF];
    float m_r[AQF], l_r[AQF];
#pragma unroll
    for (int f = 0; f < AQF; f++) {
        accA[f] = (floatx4){0.f, 0.f, 0.f, 0.f};
        accB[f] = (floatx4){0.f, 0.f, 0.f, 0.f};
        m_r[f] = -1e30f; l_r[f] = 0.f;
    }

    const int kchunk = N / KC_;
    const int kstart = c * kchunk;
    const int krow0 = ((mm >> 2) << 3) | (mm & 3);

    for (int t0 = 0; t0 < kchunk; t0 += ATILE) {
#pragma unroll
        for (int p = 0; p < 4; p++) {
            int slot = tid + p * 256;
            int kr = slot >> 3, e4 = slot & 7;
            const float* krow = qkv + (size_t)(kstart + t0 + kr) * (3 * D) + D + h * HD + e4 * 4;
            float4 kv = *(const float4*)krow;
            short4v ks;
            ks[0] = f2bf(kv.x); ks[1] = f2bf(kv.y); ks[2] = f2bf(kv.z); ks[3] = f2bf(kv.w);
            *(short4v*)&Ks[kr * KSTR + e4 * 4] = ks;
            const float* vrow = qkv + (size_t)(kstart + t0 + kr) * (3 * D) + 2 * D + h * HD + e4 * 4;
            float4 vv = *(const float4*)vrow;
            VTs[(e4 * 4 + 0) * VSTR + kr] = f2bf(vv.x);
            VTs[(e4 * 4 + 1) * VSTR + kr] = f2bf(vv.y);
            VTs[(e4 * 4 + 2) * VSTR + kr] = f2bf(vv.z);
            VTs[(e4 * 4 + 3) * VSTR + kr] = f2bf(vv.w);
        }
        __syncthreads();
#pragma unroll
        for (int s = 0; s < ATILE / 32; s++) {
            int sb = s * 32;
            short8 kf0 = *(const short8*)&Ks[(sb + krow0) * KSTR + quad * 8];
            short8 kf1 = *(const short8*)&Ks[(sb + krow0 + 4) * KSTR + quad * 8];
            short8 vf0 = *(const short8*)&VTs[mm * VSTR + sb + quad * 8];
            short8 vf1 = *(const short8*)&VTs[(mm + 16) * VSTR + sb + quad * 8];
            floatx4 zero = {0.f, 0.f, 0.f, 0.f};
#pragma unroll
            for (int f = 0; f < AQF; f++) {
                floatx4 s0 = __builtin_amdgcn_mfma_f32_16x16x32_bf16(kf0, qf[f], zero, 0, 0, 0);
                floatx4 s1 = __builtin_amdgcn_mfma_f32_16x16x32_bf16(kf1, qf[f], zero, 0, 0, 0);
                float mx = fmaxf(fmaxf(fmaxf(s0[0], s0[1]), fmaxf(s0[2], s0[3])),
                                 fmaxf(fmaxf(s1[0], s1[1]), fmaxf(s1[2], s1[3])));
                mx = fmaxf(mx, __shfl_xor(mx, 16));
                mx = fmaxf(mx, __shfl_xor(mx, 32));
                float nm = fmaxf(m_r[f], mx);
                float alpha = __expf(m_r[f] - nm);
                float p0[4], p1[4], ls = 0.f;
#pragma unroll
                for (int j = 0; j < 4; j++) {
                    p0[j] = __expf(s0[j] - nm);
                    p1[j] = __expf(s1[j] - nm);
                    ls += p0[j] + p1[j];
                }
                ls += __shfl_xor(ls, 16);
                ls += __shfl_xor(ls, 32);
                l_r[f] = l_r[f] * alpha + ls;
                m_r[f] = nm;
                short8 pf;
#pragma unroll
                for (int j = 0; j < 4; j++) { pf[j] = f2bf(p0[j]); pf[4 + j] = f2bf(p1[j]); }
#pragma unroll
                for (int j = 0; j < 4; j++) { accA[f][j] *= alpha; accB[f][j] *= alpha; }
                accA[f] = __builtin_amdgcn_mfma_f32_16x16x32_bf16(vf0, pf, accA[f], 0, 0, 0);
                accB[f] = __builtin_amdgcn_mfma_f32_16x16x32_bf16(vf1, pf, accB[f], 0, 0, 0);
            }
        }
        __syncthreads();
    }
    size_t NH = (size_t)N * H;
#pragma unroll
    for (int f = 0; f < AQF; f++) {
        int qi = qbase + f * 16 + mm;
        size_t nh = (size_t)qi * H + h;
        if (lane < 16) {
            pm[(size_t)c * NH + nh] = m_r[f];
            pl[(size_t)c * NH + nh] = l_r[f];
        }
        float* op = po + ((size_t)c * NH + nh) * HD;
#pragma unroll
        for (int j = 0; j < 4; j++) {
            op[quad * 4 + j] = accA[f][j];
            op[16 + quad * 4 + j] = accB[f][j];
        }
    }
}

// ---------------- combine partials -> obuf[N, 256] ----------------
__global__ __launch_bounds__(256) void attn_combine_kernel(
        const float* __restrict__ po, const float* __restrict__ pm,
        const float* __restrict__ pl, float* __restrict__ obuf, int N, int KC_) {
    int idx = blockIdx.x * 256 + threadIdx.x;
    int d = idx & (HD - 1);
    int nh = idx >> 5;
    size_t NH = (size_t)N * H;
    float M = -1e30f;
    for (int cc = 0; cc < KC_; cc++) M = fmaxf(M, pm[(size_t)cc * NH + nh]);
    float l = 0.f, o = 0.f;
    for (int cc = 0; cc < KC_; cc++) {
        float a = __expf(pm[(size_t)cc * NH + nh] - M);
        l += a * pl[(size_t)cc * NH + nh];
        o += a * po[((size_t)cc * NH + nh) * HD + d];
    }
    int n = nh >> 3, h = nh & (H - 1);
    obuf[(size_t)n * D + h * HD + d] = o / l;
}

// ---------------- launch ----------------
extern "C" void kernel_launch(void* const* d_in, const int* in_sizes, int n_in,
                              void* d_out, int out_size, void* d_ws, size_t ws_size,
                              hipStream_t stream) {
    const float* x    = (const float*)d_in[0];
    const int*   ei   = (const int*)d_in[1];
    const float* ea   = (const float*)d_in[2];
    const float* eps  = (const float*)d_in[3];
    const float* Wl   = (const float*)d_in[4];
    const float* bl   = (const float*)d_in[5];
    const float* W1   = (const float*)d_in[6];
    const float* b1   = (const float*)d_in[7];
    const float* W2   = (const float*)d_in[8];
    const float* b2   = (const float*)d_in[9];
    const float* lnlg = (const float*)d_in[10];
    const float* lnlb = (const float*)d_in[11];
    const float* in_w = (const float*)d_in[12];
    const float* in_b = (const float*)d_in[13];
    const float* outw = (const float*)d_in[14];
    const float* outb = (const float*)d_in[15];
    const float* lnag = (const float*)d_in[16];
    const float* lnab = (const float*)d_in[17];
    const float* Wf1  = (const float*)d_in[18];
    const float* bf1  = (const float*)d_in[19];
    const float* Wf2  = (const float*)d_in[20];
    const float* bf2  = (const float*)d_in[21];
    const float* lnfg = (const float*)d_in[22];
    const float* lnfb = (const float*)d_in[23];
    float* out = (float*)d_out;

    const int N = in_sizes[0] / D;       // 4096
    const int E = in_sizes[1] / 2;       // 262144
    const size_t NF = (size_t)N * D;     // 1048576
    const size_t NH = (size_t)N * H;

    const int KCsel = 8;
    size_t floatEnd = (4 + (size_t)KCsel) * NF + 2 * (size_t)KCsel * NH;
    size_t offB = (floatEnd * 4 + 15) & ~(size_t)15;
    size_t intCount = (size_t)N + 3 * (size_t)E + (size_t)(N + 1);
    size_t wltOff = (offB + intCount * 4 + 15) & ~(size_t)15;

    float* w = (float*)d_ws;
    float* x1   = w;
    float* qkv  = w + NF;
    float* h    = w + 4 * NF;
    float* t1   = w + 5 * NF;
    float* t2   = w + 6 * NF;
    float* po   = w + 4 * NF;
    float* pm   = w + (4 + (size_t)KCsel) * NF;
    float* pl   = pm + (size_t)KCsel * NH;
    float* obuf = w + NF;
    float* t3   = w + 2 * NF;
    float* x2   = w + 3 * NF;
    float* f1   = w + 4 * NF;
    float* f2   = w + 6 * NF;

    char* base = (char*)d_ws;
    int* ibase  = (int*)(base + offB);
    int* cnt    = ibase;
    int* perm   = ibase + N;
    int* srcp   = perm + E;
    int* dstp   = srcp + E;
    int* offs   = dstp + E;
    short* WlT    = (short*)(base + wltOff);   // 16384
    short* W1bt   = WlT + 16384;
    short* W2bt   = W1bt + 65536;
    short* inwbt  = W2bt + 65536;
    short* outwbt = inwbt + 196608;
    short* Wf1bt  = outwbt + 65536;
    short* Wf2bt  = Wf1bt + 131072;

    // --- fused prep ---
    {
        int total = 671744 + N + (int)NF;
        prep_kernel<<<(total + 255) / 256, 256, 0, stream>>>(
            Wl, W1, W2, in_w, outw, Wf1, Wf2, x, eps,
            WlT, W1bt, W2bt, inwbt, outwbt, Wf1bt, Wf2bt, cnt, h, N, (int)NF);
    }
    // --- edge binning ---
    hist_kernel<<<(E + 255) / 256, 256, 0, stream>>>(ei, cnt, E);
    scan_kernel<<<1, 1024, 0, stream>>>(cnt, offs);
    scatter_kernel<<<(E + 255) / 256, 256, 0, stream>>>(ei, cnt, perm, srcp, dstp, E);
    // --- fused GINE ---
    edge_fused_kernel<<<E / (64 * TPB), 256, 0, stream>>>(ea, WlT, bl, x, perm, srcp, dstp, h);
    // --- local MLP ---
    gemm_bf16_kernel<2><<<dim3(D / 64, N / 64), 256, 0, stream>>>(h, W1bt, b1, t1, N, D, D);
    gemm_bf16_kernel<0><<<dim3(D / 64, N / 64), 256, 0, stream>>>(t1, W2bt, b2, t2, N, D, D);
    ln_res_kernel<2><<<N, 256, 0, stream>>>(t2, x, lnlg, lnlb, x1);
    // --- attention ---
    gemm_bf16_kernel<0><<<dim3(3 * D / 64, N / 64), 256, 0, stream>>>(x1, inwbt, in_b, qkv, N, D, 3 * D);
    attn_mfma_kernel<<<dim3(N / 256, H, KCsel), 256, 0, stream>>>(qkv, po, pm, pl, N, KCsel);
    attn_combine_kernel<<<(int)(NF / 256), 256, 0, stream>>>(po, pm, pl, obuf, N, KCsel);
    gemm_bf16_kernel<0><<<dim3(D / 64, N / 64), 256, 0, stream>>>(obuf, outwbt, outb, t3, N, D, D);
    ln_res_kernel<0><<<N, 256, 0, stream>>>(t3, x1, lnag, lnab, x2);
    // --- FFN ---
    gemm_bf16_kernel<3><<<dim3(2 * D / 64, N / 64), 256, 0, stream>>>(x2, Wf1bt, bf1, f1, N, D, 2 * D);
    gemm_bf16_kernel<0><<<dim3(D / 64, N / 64), 256, 0, stream>>>(f1, Wf2bt, bf2, f2, N, 2 * D, D);
    ln_res_kernel<0><<<N, 256, 0, stream>>>(f2, x2, lnfg, lnfb, out);

    (void)n_in; (void)out_size; (void)ws_size;
}